// Round 8
// baseline (153.401 us; speedup 1.0000x reference)
//
#include <hip/hip_runtime.h>
#include <hip/hip_bf16.h>
#include <stdint.h>

#define S_LEN 2048
#define D_DIM 1024
#define P_DIM 256
#define NQ_   8192
#define M_TOT 16384  // B*S

#define BM 32
#define BN 128   // N-split: 2 blocks cover P=256
#define BK 64

typedef __attribute__((ext_vector_type(4))) float  f32x4;
typedef __attribute__((ext_vector_type(8))) __bf16 bf16x8;
typedef __attribute__((ext_vector_type(4))) __bf16 bf16x4;

__device__ __forceinline__ void async16(const void* g, void* l) {
    __builtin_amdgcn_global_load_lds(
        (const __attribute__((address_space(1))) uint32_t*)g,
        (__attribute__((address_space(3))) uint32_t*)l, 16, 0, 0);
}

__device__ __forceinline__ void nts(f32x4 v, float* p) {
    __builtin_nontemporal_store(v, (f32x4*)p);
}

// ---------------- Kernel 0: W [1024][256] f32 -> WT [256][1024] bf16 ----------
__global__ __launch_bounds__(1024) void wt_kernel(const float* __restrict__ W,
                                                  __bf16* __restrict__ WT) {
    __shared__ __bf16 tile[32][33];
    const int k0 = blockIdx.x * 32;
    const int n0 = blockIdx.y * 32;
    const int tx = threadIdx.x, ty = threadIdx.y;
    tile[ty][tx] = (__bf16)W[(k0 + ty) * P_DIM + (n0 + tx)];
    __syncthreads();
    WT[(n0 + ty) * D_DIM + (k0 + tx)] = tile[tx][ty];
}

// ---------------- Kernel 1: H(bf16) = A @ W + b  ------------------------------
// R7 skeleton; R8 change: BN 256->128, grid 512->1024 => 4 blocks/CU,
// 16 waves/CU (2x concurrency — the only lever not yet exercised; empirical
// law: per-CU mem throughput ~ waves in flight).
//  - B frags: global->VGPR each step (L2/LLC), fine-grained vmcnt via compiler.
//  - A: async global_load_lds fp32 double-buffer, XOR-16 global-side swizzle.
// Wave w owns cols nbase + w*32 .. +32 (2 n-tiles). 8 MFMA/wave/step.
__global__ __launch_bounds__(256, 4) void gemm_kernel(const float*  __restrict__ A,
                                                      const __bf16* __restrict__ WT,
                                                      const float*  __restrict__ bias,
                                                      __bf16*       __restrict__ H) {
    __shared__ float As[2][BM * BK];   // 8 KB x2, fp32, XOR-swizzled 16B chunks

    const int tid = threadIdx.x;
    const int w   = tid >> 6;
    const int l   = tid & 63;
    const int lm  = l & 15;
    const int q   = l >> 4;

    const int m0    = (blockIdx.x >> 1) * BM;
    const int nbase = (blockIdx.x & 1) * BN;

    // ---- A async staging: wave w issues insts j=2w,2w+1; inst j covers rows
    // 4j..4j+3. Lane l -> row 4j+(l>>4), dest chunk l&15 = k-chunk (l&15)^(row&15).
    auto stageA = [&](int buf, int k0) {
        #pragma unroll
        for (int jj = 0; jj < 2; ++jj) {
            const int j = 2 * w + jj;
            const int r = 4 * j + (l >> 4);
            const int c = (l & 15) ^ (r & 15);
            async16(A + (size_t)(m0 + r) * D_DIM + k0 + c * 4,
                    &As[buf][j * 256]);
        }
    };

    f32x4 acc[2][2] = {};

    const __bf16* wp = WT + (size_t)(nbase + w * 32 + lm) * D_DIM + q * 8;

    auto step = [&](int buf, int k0, int kstage) {
        // ---- B frags: 4x global_load_dwordx4 (issued FIRST)
        bf16x8 rb[2][2];
        #pragma unroll
        for (int kh = 0; kh < 2; ++kh)
            #pragma unroll
            for (int ni = 0; ni < 2; ++ni)
                rb[kh][ni] = *(const bf16x8*)(wp + (size_t)ni * 16 * D_DIM + k0 + kh * 32);
        // ---- A stage for next step (in-order vmcnt: B waits leave A in flight)
        if (kstage >= 0) stageA(buf ^ 1, kstage);
        __builtin_amdgcn_sched_barrier(0);
        // ---- compute: ds_read A (swizzled), cvt->bf16, 8 MFMAs
        #pragma unroll
        for (int kh = 0; kh < 2; ++kh) {
            bf16x8 af[2];
            #pragma unroll
            for (int mi = 0; mi < 2; ++mi) {
                const int row = mi * 16 + lm;
                const int c0  = kh * 8 + q * 2;
                const f32x4 a0 = *(const f32x4*)(&As[buf][row * BK + ((c0 ^ lm) * 4)]);
                const f32x4 a1 = *(const f32x4*)(&As[buf][row * BK + (((c0 + 1) ^ lm) * 4)]);
                af[mi][0] = (__bf16)a0[0]; af[mi][1] = (__bf16)a0[1];
                af[mi][2] = (__bf16)a0[2]; af[mi][3] = (__bf16)a0[3];
                af[mi][4] = (__bf16)a1[0]; af[mi][5] = (__bf16)a1[1];
                af[mi][6] = (__bf16)a1[2]; af[mi][7] = (__bf16)a1[3];
            }
            #pragma unroll
            for (int mi = 0; mi < 2; ++mi)
                #pragma unroll
                for (int ni = 0; ni < 2; ++ni)
                    acc[mi][ni] = __builtin_amdgcn_mfma_f32_16x16x32_bf16(
                        af[mi], rb[kh][ni], acc[mi][ni], 0, 0, 0);
        }
        __syncthreads();   // drains the 2 stageA insts (issued a full step ago)
    };

    stageA(0, 0);
    __syncthreads();

    #pragma unroll 1
    for (int ph = 0; ph < 7; ++ph) {
        step(0, (2 * ph) * BK,     (2 * ph + 1) * BK);
        step(1, (2 * ph + 1) * BK, (2 * ph + 2) * BK);
    }
    step(0, 14 * BK, 15 * BK);
    step(1, 15 * BK, -1);

    // ---- epilogue: D layout row = q*4 + r, col = lane&15; bf16 store
    #pragma unroll
    for (int ni = 0; ni < 2; ++ni) {
        const int col = nbase + w * 32 + ni * 16 + lm;
        const float bv = bias[col];
        #pragma unroll
        for (int mi = 0; mi < 2; ++mi) {
            const int rbase = m0 + mi * 16 + q * 4;
            #pragma unroll
            for (int r = 0; r < 4; ++r)
                H[(size_t)(rbase + r) * P_DIM + col] = (__bf16)(acc[mi][ni][r] + bv);
        }
    }
}

// ---------------- Kernel 2: span gather (bf16 H -> f32 out) -------------------
__global__ __launch_bounds__(256) void gather_kernel(const __bf16* __restrict__ H,
                                                     const int* __restrict__ s1,
                                                     const int* __restrict__ e1,
                                                     const int* __restrict__ qb,
                                                     const int* __restrict__ s2,
                                                     const int* __restrict__ e2,
                                                     float* __restrict__ out) {
    const int wave = (blockIdx.x * 256 + threadIdx.x) >> 6;  // 0..2047
    const int l    = threadIdx.x & 63;

    #pragma unroll
    for (int j = 0; j < 8; ++j) {
        const int p   = wave * 8 + j;       // 0..16383
        const int set = p >> 13;
        const int qi  = p & 8191;
        const int s   = set ? s2[qi] : s1[qi];
        const int e   = set ? e2[qi] : e1[qi];
        const int b   = qb[qi];

        f32x4 v0 = {0.f, 0.f, 0.f, 0.f}, v1 = v0;
        if (e >= s) {   // wave-uniform branch
            const bf16x4 a = *(const bf16x4*)(H + ((size_t)b * S_LEN + s) * P_DIM + l * 4);
            const bf16x4 c = *(const bf16x4*)(H + ((size_t)b * S_LEN + e) * P_DIM + l * 4);
            v0[0] = (float)a[0]; v0[1] = (float)a[1]; v0[2] = (float)a[2]; v0[3] = (float)a[3];
            v1[0] = (float)c[0]; v1[1] = (float)c[1]; v1[2] = (float)c[2]; v1[3] = (float)c[3];
        }
        float* op = out + (size_t)set * (NQ_ * 512) + (size_t)qi * 512;
        nts(v0, op + l * 4);
        nts(v1, op + 256 + l * 4);
    }
}

// ---------------- launch ------------------------------------------------------
extern "C" void kernel_launch(void* const* d_in, const int* in_sizes, int n_in,
                              void* d_out, int out_size, void* d_ws, size_t ws_size,
                              hipStream_t stream) {
    const float* A    = (const float*)d_in[1];
    const int*   s1   = (const int*)  d_in[2];
    const int*   e1   = (const int*)  d_in[3];
    const int*   qb   = (const int*)  d_in[4];
    const int*   s2   = (const int*)  d_in[5];
    const int*   e2   = (const int*)  d_in[6];
    const float* W    = (const float*)d_in[7];
    const float* bias = (const float*)d_in[8];
    float*       out  = (float*)d_out;

    __bf16* WT = (__bf16*)d_ws;                        // 512 KB
    __bf16* H  = (__bf16*)((char*)d_ws + (1 << 20));   // 8 MB bf16

    wt_kernel    <<<dim3(32, 8), dim3(32, 32), 0, stream>>>(W, WT);
    gemm_kernel  <<<dim3((M_TOT / BM) * 2), dim3(256), 0, stream>>>(A, WT, bias, H);
    gather_kernel<<<dim3(512), dim3(256), 0, stream>>>(H, s1, e1, qb, s2, e2, out);
}

// Round 9
// 151.773 us; speedup vs baseline: 1.0107x; 1.0107x over previous
//
#include <hip/hip_runtime.h>
#include <hip/hip_bf16.h>
#include <stdint.h>

#define S_LEN 2048
#define D_DIM 1024
#define P_DIM 256
#define NQ_   8192
#define M_TOT 16384  // B*S

#define BM 64
#define BN 256
#define BK 64

typedef __attribute__((ext_vector_type(4))) float  f32x4;
typedef __attribute__((ext_vector_type(8))) __bf16 bf16x8;
typedef __attribute__((ext_vector_type(4))) __bf16 bf16x4;

__device__ __forceinline__ void async16(const void* g, void* l) {
    __builtin_amdgcn_global_load_lds(
        (const __attribute__((address_space(1))) uint32_t*)g,
        (__attribute__((address_space(3))) uint32_t*)l, 16, 0, 0);
}

__device__ __forceinline__ void nts(f32x4 v, float* p) {
    __builtin_nontemporal_store(v, (f32x4*)p);
}

// ---------------- Kernel 0: W [1024][256] f32 -> WT [256][1024] bf16 ----------
__global__ __launch_bounds__(1024) void wt_kernel(const float* __restrict__ W,
                                                  __bf16* __restrict__ WT) {
    __shared__ __bf16 tile[32][33];
    const int k0 = blockIdx.x * 32;
    const int n0 = blockIdx.y * 32;
    const int tx = threadIdx.x, ty = threadIdx.y;
    tile[ty][tx] = (__bf16)W[(k0 + ty) * P_DIM + (n0 + tx)];
    __syncthreads();
    WT[(n0 + ty) * D_DIM + (k0 + tx)] = tile[tx][ty];
}

// ---------------- Kernel 1: H(bf16) = A @ W + b  ------------------------------
// R9: minimize bytes/CU/step (per-CU mem rate is pinned ~13.5 B/cy at >=8
// waves/CU — R1/R4/R7/R8 invariant). BM=64,BN=256,BK=64, 512 thr = 8 waves,
// grid=256 -> 1 block/CU, ZERO A/B duplication: 48 KB/CU/step (vs 80-96).
// B total 268->128 MB, A 64 MB read once.
//  - B frags: global->VGPR (L2), fine-grained vmcnt by compiler.
//  - A: async global_load_lds fp32 double-buffer, XOR-16 global-side swizzle
//    (R7-proven: 0 bank conflicts). Stage issued early; barrier drains it a
//    full compute-phase later.
// Wave w: m-half (w>>2)*32, n-quarter (w&3)*64 -> 2m x 4n tiles, 16 MFMA/step.
__global__ __launch_bounds__(512, 2) void gemm_kernel(const float*  __restrict__ A,
                                                      const __bf16* __restrict__ WT,
                                                      const float*  __restrict__ bias,
                                                      __bf16*       __restrict__ H) {
    __shared__ float As[2][BM * BK];   // 16 KB x2, fp32, XOR-swizzled 16B chunks

    const int tid = threadIdx.x;
    const int w   = tid >> 6;     // 0..7
    const int l   = tid & 63;
    const int lm  = l & 15;
    const int q   = l >> 4;
    const int mh  = w >> 2;       // m-half
    const int nq  = w & 3;        // n-quarter

    const int m0 = blockIdx.x * BM;

    // ---- A async staging: 16 insts (2/wave); inst j covers rows 4j..4j+3.
    // Lane l -> row 4j+(l>>4), dest pos l&15 holds k-chunk (l&15)^(row&15).
    auto stageA = [&](int buf, int k0) {
        #pragma unroll
        for (int jj = 0; jj < 2; ++jj) {
            const int j = 2 * w + jj;
            const int r = 4 * j + (l >> 4);
            const int c = (l & 15) ^ (r & 15);
            async16(A + (size_t)(m0 + r) * D_DIM + k0 + c * 4,
                    &As[buf][j * 256]);
        }
    };

    f32x4 acc[2][4] = {};

    const __bf16* wp = WT + (size_t)(nq * 64 + lm) * D_DIM + q * 8;

    auto step = [&](int buf, int k0, int kstage) {
        // ---- B frags: 8x global_load_dwordx4 (issued FIRST)
        bf16x8 rb[2][4];
        #pragma unroll
        for (int kh = 0; kh < 2; ++kh)
            #pragma unroll
            for (int ni = 0; ni < 4; ++ni)
                rb[kh][ni] = *(const bf16x8*)(wp + (size_t)ni * 16 * D_DIM + k0 + kh * 32);
        // ---- A stage for next step (after B: in-order vmcnt leaves A in flight
        //      through the B-consumption waits; barrier drains it at step end)
        if (kstage >= 0) stageA(buf ^ 1, kstage);
        __builtin_amdgcn_sched_barrier(0);
        // ---- compute: ds_read A (swizzled), cvt->bf16, 16 MFMAs
        #pragma unroll
        for (int kh = 0; kh < 2; ++kh) {
            bf16x8 af[2];
            #pragma unroll
            for (int mi = 0; mi < 2; ++mi) {
                const int row = mh * 32 + mi * 16 + lm;
                const int c0  = kh * 8 + q * 2;
                const f32x4 a0 = *(const f32x4*)(&As[buf][row * BK + (((c0    ) ^ lm) * 4)]);
                const f32x4 a1 = *(const f32x4*)(&As[buf][row * BK + (((c0 + 1) ^ lm) * 4)]);
                af[mi][0] = (__bf16)a0[0]; af[mi][1] = (__bf16)a0[1];
                af[mi][2] = (__bf16)a0[2]; af[mi][3] = (__bf16)a0[3];
                af[mi][4] = (__bf16)a1[0]; af[mi][5] = (__bf16)a1[1];
                af[mi][6] = (__bf16)a1[2]; af[mi][7] = (__bf16)a1[3];
            }
            #pragma unroll
            for (int mi = 0; mi < 2; ++mi)
                #pragma unroll
                for (int ni = 0; ni < 4; ++ni)
                    acc[mi][ni] = __builtin_amdgcn_mfma_f32_16x16x32_bf16(
                        af[mi], rb[kh][ni], acc[mi][ni], 0, 0, 0);
        }
        __syncthreads();   // drains the 2 stageA insts (issued a compute-phase ago)
    };

    stageA(0, 0);
    __syncthreads();

    #pragma unroll 1
    for (int ph = 0; ph < 7; ++ph) {
        step(0, (2 * ph) * BK,     (2 * ph + 1) * BK);
        step(1, (2 * ph + 1) * BK, (2 * ph + 2) * BK);
    }
    step(0, 14 * BK, 15 * BK);
    step(1, 15 * BK, -1);

    // ---- epilogue: D layout row = q*4 + r, col = lane&15; bf16 store
    #pragma unroll
    for (int ni = 0; ni < 4; ++ni) {
        const int col = nq * 64 + ni * 16 + lm;
        const float bv = bias[col];
        #pragma unroll
        for (int mi = 0; mi < 2; ++mi) {
            const int rbase = m0 + mh * 32 + mi * 16 + q * 4;
            #pragma unroll
            for (int r = 0; r < 4; ++r)
                H[(size_t)(rbase + r) * P_DIM + col] = (__bf16)(acc[mi][ni][r] + bv);
        }
    }
}

// ---------------- Kernel 2: span gather (bf16 H -> f32 out) -------------------
__global__ __launch_bounds__(256) void gather_kernel(const __bf16* __restrict__ H,
                                                     const int* __restrict__ s1,
                                                     const int* __restrict__ e1,
                                                     const int* __restrict__ qb,
                                                     const int* __restrict__ s2,
                                                     const int* __restrict__ e2,
                                                     float* __restrict__ out) {
    const int wave = (blockIdx.x * 256 + threadIdx.x) >> 6;  // 0..2047
    const int l    = threadIdx.x & 63;

    #pragma unroll
    for (int j = 0; j < 8; ++j) {
        const int p   = wave * 8 + j;       // 0..16383
        const int set = p >> 13;
        const int qi  = p & 8191;
        const int s   = set ? s2[qi] : s1[qi];
        const int e   = set ? e2[qi] : e1[qi];
        const int b   = qb[qi];

        f32x4 v0 = {0.f, 0.f, 0.f, 0.f}, v1 = v0;
        if (e >= s) {   // wave-uniform branch
            const bf16x4 a = *(const bf16x4*)(H + ((size_t)b * S_LEN + s) * P_DIM + l * 4);
            const bf16x4 c = *(const bf16x4*)(H + ((size_t)b * S_LEN + e) * P_DIM + l * 4);
            v0[0] = (float)a[0]; v0[1] = (float)a[1]; v0[2] = (float)a[2]; v0[3] = (float)a[3];
            v1[0] = (float)c[0]; v1[1] = (float)c[1]; v1[2] = (float)c[2]; v1[3] = (float)c[3];
        }
        float* op = out + (size_t)set * (NQ_ * 512) + (size_t)qi * 512;
        nts(v0, op + l * 4);
        nts(v1, op + 256 + l * 4);
    }
}

// ---------------- launch ------------------------------------------------------
extern "C" void kernel_launch(void* const* d_in, const int* in_sizes, int n_in,
                              void* d_out, int out_size, void* d_ws, size_t ws_size,
                              hipStream_t stream) {
    const float* A    = (const float*)d_in[1];
    const int*   s1   = (const int*)  d_in[2];
    const int*   e1   = (const int*)  d_in[3];
    const int*   qb   = (const int*)  d_in[4];
    const int*   s2   = (const int*)  d_in[5];
    const int*   e2   = (const int*)  d_in[6];
    const float* W    = (const float*)d_in[7];
    const float* bias = (const float*)d_in[8];
    float*       out  = (float*)d_out;

    __bf16* WT = (__bf16*)d_ws;                        // 512 KB
    __bf16* H  = (__bf16*)((char*)d_ws + (1 << 20));   // 8 MB bf16

    wt_kernel    <<<dim3(32, 8), dim3(32, 32), 0, stream>>>(W, WT);
    gemm_kernel  <<<dim3(M_TOT / BM), dim3(512), 0, stream>>>(A, WT, bias, H);
    gather_kernel<<<dim3(512), dim3(256), 0, stream>>>(H, s1, e1, qb, s2, e2, out);
}